// Round 8
// baseline (95.494 us; speedup 1.0000x reference)
//
#include <hip/hip_runtime.h>
#include <hip/hip_bf16.h>
#include <stdint.h>
#include <stddef.h>

// NT-Xent loss, B=4096, D=256, N=8192, T=0.5.
// normalize(+zero sumexp) -> fused symmetric ZZ^T GEMM + exp row/col-sum +
// positive capture -> 1-block finalize/mean. No NxN materialization.
//
// R15: COUNTED-VMCNT K-HALF PIPELINE (T3/T4) + ATOMICS OUT OF LOOP.
// R12 (8 bar/tile) and R14 (1 bar/tile) both land ~33-35 us -> bound is
// neither barriers nor LDS reads but EXPOSED LATENCY: per-tile 64 KB L2
// staging (~1200+ cyc) drained to vmcnt(0) every tile, plus in-loop global
// atomics right before the drain. Fixes:
//  (a) tiles split into two 32 KB K-halves; 4 rotating half-buffers;
//      per half: issue stage(h+2) -> s_waitcnt vmcnt(8) (only half h
//      guaranteed; h+1,h+2 stay IN FLIGHT across the barrier - never
//      vmcnt(0) in the loop, m218's +38-73% lever) -> s_barrier -> compute.
//  (b) colsum -> LDS accumulator (ds atomics), ONE global flush at end.
//  (c) acc quadrants finalize per half-1 phase -> epilogue slices overlap
//      next quadrant's MFMAs (R14 mechanism); only Q3 carries one tile.
// Carry-overs: 4x2 wave geometry (af[2][8]=64 regs, no spill), A-bounce
// through LDS, XOR-swizzled conflict-free LDS (swizzle on global source),
// symmetry (2080 tile-pairs), balanced tail (s=32 halves on cj2/cj3),
// exp-scale folded into normalize (e = exp2(dot'), pos = dot'*ln2).

#define B_ROWS 4096
#define D_DIM  256
#define N_ROWS 8192
#define BM 128

typedef __bf16 bf16;
typedef bf16  bf16x8  __attribute__((ext_vector_type(8)));
typedef bf16  bf16x4  __attribute__((ext_vector_type(4)));
typedef float floatx4 __attribute__((ext_vector_type(4)));

// ---------------------------------------------------------------- normalize
__global__ __launch_bounds__(256) void normalize_kernel(
    const float* __restrict__ z_i, const float* __restrict__ z_j,
    bf16* __restrict__ zn, float* __restrict__ sumexp) {
  const int wave = threadIdx.x >> 6;
  const int lane = threadIdx.x & 63;
  const int row  = blockIdx.x * 4 + wave;
  const float* src = (row < B_ROWS) ? (z_i + (size_t)row * D_DIM)
                                    : (z_j + (size_t)(row - B_ROWS) * D_DIM);
  float4 v = ((const float4*)src)[lane];
  float ss = v.x * v.x + v.y * v.y + v.z * v.z + v.w * v.w;
  #pragma unroll
  for (int m = 1; m < 64; m <<= 1) ss += __shfl_xor(ss, m);
  const float rn = rsqrtf(ss) * 1.6986436f;  // * sqrt(2/ln2)
  bf16x4 o;
  o[0] = (bf16)(v.x * rn);
  o[1] = (bf16)(v.y * rn);
  o[2] = (bf16)(v.z * rn);
  o[3] = (bf16)(v.w * rn);
  ((bf16x4*)(zn + (size_t)row * D_DIM))[lane] = o;
  if (lane == 0) sumexp[row] = 0.f;
}

// ------------------------------------------------------- fused sim+exp+sum
// Grid: 64 ri x 4 cj = 256 blocks (1/CU, ~136 KB LDS). Block (ri,cj): 8
// tiles s=8cj+t; (ri<32, cj>=2) add the j64-half (cj-2) of s=32 (tail).
// 8 waves in 4x2 (wave = 32 rows x 64 cols). Halves h=0..15: half h lives
// in H[(h+2)&3]; stage(h+2) targets H[h&3]. Half-buffer layout: row n
// (0..127) x swizzled k-chunk lcs (0..15): element n*128 + lcs*8, with
// lc = (lcs&8)|((lcs&7)^(n&7)), k = kh*128 + lc*8.. (swizzle on source).
__global__ __launch_bounds__(512, 2) void simexp_kernel(
    const bf16* __restrict__ zn, float* __restrict__ sumexp,
    float* __restrict__ pos) {
  __shared__ __align__(16) bf16 Hs[4][128 * 128];  // 4 x 32 KB
  __shared__ float colsum_s[9 * 128];              // 4.5 KB (8 tiles + tail)

  const int tid   = threadIdx.x;
  const int wave  = tid >> 6;
  const int lane  = tid & 63;
  const int lcol  = lane & 15;
  const int lquad = lane >> 4;
  const int wr = (wave >> 1) * 32;  // wave row offset: 0,32,64,96
  const int wc = (wave & 1) * 64;   // wave col offset: 0,64
  const int ri = blockIdx.x >> 2;
  const int cj = blockIdx.x & 3;
  const int row_base = ri * BM;
  const bool has_tail = (ri < 32 && cj >= 2);

  auto ct_of = [&](int t) { return (ri + 8 * cj + t) & 63; };

  // stage one K-half (128 rows x 128 k = 32 KB): 4 x 16B per thread.
  auto stage_half = [&](int buf, const bf16* src, int kh) {
    #pragma unroll
    for (int it = 0; it < 4; ++it) {
      const int s   = it * 512 + tid;   // 0..2047
      const int n   = s >> 4;           // row 0..127
      const int lcs = s & 15;           // swizzled local chunk
      const int lc  = (lcs & 8) | ((lcs & 7) ^ (n & 7));
      __builtin_amdgcn_global_load_lds(
          (const __attribute__((address_space(1))) unsigned int*)
              (src + (size_t)n * D_DIM + kh * 128 + lc * 8),
          (__attribute__((address_space(3))) unsigned int*)&Hs[buf][s * 8],
          16, 0, 0);
    }
  };
  // stage the 64-row x 256-k tail tile (32 KB), full-K swizzled layout.
  auto stage_tail = [&](int buf, const bf16* src) {
    #pragma unroll
    for (int it = 0; it < 4; ++it) {
      const int s   = it * 512 + tid;
      const int n   = s >> 5;           // row 0..63
      const int kcs = s & 31;
      const int kc  = (kcs & 24) | ((kcs & 7) ^ (n & 7));
      __builtin_amdgcn_global_load_lds(
          (const __attribute__((address_space(1))) unsigned int*)
              (src + (size_t)n * D_DIM + kc * 8),
          (__attribute__((address_space(3))) unsigned int*)&Hs[buf][s * 8],
          16, 0, 0);
    }
  };

  // ---- prologue: A k-halves -> H0,H1; B tile0 k-halves -> H2,H3.
  const bf16* Abase  = zn + (size_t)row_base * D_DIM;
  const bf16* B0base = zn + (size_t)ct_of(0) * BM * D_DIM;
  stage_half(0, Abase, 0);
  stage_half(1, Abase, 1);
  stage_half(2, B0base, 0);
  stage_half(3, B0base, 1);
  #pragma unroll 1
  for (int s = tid; s < 9 * 128; s += 512) colsum_s[s] = 0.f;
  asm volatile("s_waitcnt vmcnt(8)" ::: "memory");  // A resident; B0 in flight
  __builtin_amdgcn_sched_barrier(0);
  __builtin_amdgcn_s_barrier();

  // af[ti][kq] from H0/H1 (backing overwritten later -> pinned in regs).
  floatx4 af[2][8];
  #pragma unroll
  for (int ti = 0; ti < 2; ++ti) {
    const int n = wr + ti * 16 + lcol;
    #pragma unroll
    for (int kq = 0; kq < 8; ++kq) {
      const int kql = kq & 3;
      const int lc  = kql * 4 + lquad;
      const int lcs = (lc & 8) | ((lc & 7) ^ (n & 7));
      af[ti][kq] = *(const floatx4*)(&Hs[kq >> 2][n * 128 + lcs * 8]);
    }
  }
  asm volatile("s_waitcnt lgkmcnt(0)" ::: "memory");  // af reads complete
  __builtin_amdgcn_sched_barrier(0);
  __builtin_amdgcn_s_barrier();  // before any wave stages over H0/H1

  float rowsum[2][4];
  #pragma unroll
  for (int ti = 0; ti < 2; ++ti)
    #pragma unroll
    for (int r = 0; r < 4; ++r) rowsum[ti][r] = 0.f;

#define MFMA_(A, B_, C) __builtin_amdgcn_mfma_f32_16x16x32_bf16( \
    __builtin_bit_cast(bf16x8, A), B_, C, 0, 0, 0)

  // one quadrant of one K-half: 4 ds_read_b128 + 8 MFMA.
#define QPHASE(ACC, Q, KH, BB)                                            \
  {                                                                       \
    const int n = wc + (Q) * 16 + lcol;                                   \
    bf16x8 b0, b1, b2, b3;                                                \
    { const int lc = 0 * 4 + lquad;                                       \
      b0 = *(const bf16x8*)((BB) + n * 128 +                              \
           (((lc & 8) | ((lc & 7) ^ (n & 7))) * 8)); }                    \
    { const int lc = 1 * 4 + lquad;                                       \
      b1 = *(const bf16x8*)((BB) + n * 128 +                              \
           (((lc & 8) | ((lc & 7) ^ (n & 7))) * 8)); }                    \
    { const int lc = 2 * 4 + lquad;                                       \
      b2 = *(const bf16x8*)((BB) + n * 128 +                              \
           (((lc & 8) | ((lc & 7) ^ (n & 7))) * 8)); }                    \
    { const int lc = 3 * 4 + lquad;                                       \
      b3 = *(const bf16x8*)((BB) + n * 128 +                              \
           (((lc & 8) | ((lc & 7) ^ (n & 7))) * 8)); }                    \
    __builtin_amdgcn_s_setprio(1);                                        \
    ACC[0] = MFMA_(af[0][(KH)*4 + 0], b0, ACC[0]);                        \
    ACC[1] = MFMA_(af[1][(KH)*4 + 0], b0, ACC[1]);                        \
    ACC[0] = MFMA_(af[0][(KH)*4 + 1], b1, ACC[0]);                        \
    ACC[1] = MFMA_(af[1][(KH)*4 + 1], b1, ACC[1]);                        \
    ACC[0] = MFMA_(af[0][(KH)*4 + 2], b2, ACC[0]);                        \
    ACC[1] = MFMA_(af[1][(KH)*4 + 2], b2, ACC[1]);                        \
    ACC[0] = MFMA_(af[0][(KH)*4 + 3], b3, ACC[0]);                        \
    ACC[1] = MFMA_(af[1][(KH)*4 + 3], b3, ACC[1]);                        \
    __builtin_amdgcn_s_setprio(0);                                        \
  }

  // epilogue slice of a finished quadrant: exp + rowsum + LDS colsum.
#define SLICE(ACC, Q, SLOT, COLB, DG)                                     \
  {                                                                       \
    float cs = 0.f;                                                       \
    _Pragma("unroll")                                                     \
    for (int ti = 0; ti < 2; ++ti) {                                      \
      _Pragma("unroll")                                                   \
      for (int r = 0; r < 4; ++r) {                                       \
        const float v = ACC[ti][r];                                       \
        float e = __builtin_amdgcn_exp2f(v);                              \
        if (DG) {                                                         \
          const int rg = row_base + wr + ti * 16 + lquad * 4 + r;         \
          const int cg = (COLB) + wc + (Q) * 16 + lcol;                   \
          if (cg == rg) e = 0.f;                                          \
        }                                                                 \
        rowsum[ti][r] += e;                                               \
        cs += e;                                                          \
      }                                                                   \
    }                                                                     \
    cs += __shfl_xor(cs, 16);                                             \
    cs += __shfl_xor(cs, 32);                                             \
    if (!(DG) && lquad == 0)                                              \
      atomicAdd(&colsum_s[(SLOT) + wc + (Q) * 16 + lcol], cs);            \
  }

  floatx4 acc0[2], acc1[2], acc2[2], acc3[2];
  floatx4 car[2];              // tile-carried Q3 accumulator
  int  pslot3 = 0, pcolb3 = 0;
  bool pdiag3 = false;

  #pragma unroll 1
  for (int t = 0; t < 8; ++t) {
    const int  colb = ct_of(t) * BM;
    const bool diag = (cj == 0 && t == 0);

    // -------- half 0 (h = 2t, buffer H[(2t+2)&3]) --------
    {
      const int h = 2 * t;
      if (t < 7) {
        stage_half(h & 3, zn + (size_t)ct_of(t + 1) * BM * D_DIM, 0);
        asm volatile("s_waitcnt vmcnt(8)" ::: "memory");
      } else if (has_tail) {
        stage_tail(h & 3,
                   zn + (size_t)((ri + 32) * BM + (cj - 2) * 64) * D_DIM);
        asm volatile("s_waitcnt vmcnt(8)" ::: "memory");
      } else {
        asm volatile("s_waitcnt vmcnt(4)" ::: "memory");
      }
      __builtin_amdgcn_sched_barrier(0);
      __builtin_amdgcn_s_barrier();
      const bf16* bb = &Hs[(h + 2) & 3][0];
      #pragma unroll
      for (int ti = 0; ti < 2; ++ti) {
        acc0[ti] = floatx4{0.f, 0.f, 0.f, 0.f};
        acc1[ti] = floatx4{0.f, 0.f, 0.f, 0.f};
        acc2[ti] = floatx4{0.f, 0.f, 0.f, 0.f};
        acc3[ti] = floatx4{0.f, 0.f, 0.f, 0.f};
      }
      QPHASE(acc0, 0, 0, bb)
      QPHASE(acc1, 1, 0, bb)
      QPHASE(acc2, 2, 0, bb)
      QPHASE(acc3, 3, 0, bb)
    }

    // -------- half 1 (h = 2t+1, buffer H[(2t+3)&3]) --------
    {
      const int h = 2 * t + 1;
      if (t < 7) {
        stage_half(h & 3, zn + (size_t)ct_of(t + 1) * BM * D_DIM, 1);
        asm volatile("s_waitcnt vmcnt(8)" ::: "memory");
      } else if (has_tail) {
        asm volatile("s_waitcnt vmcnt(4)" ::: "memory");
      } else {
        asm volatile("s_waitcnt vmcnt(0)" ::: "memory");
      }
      __builtin_amdgcn_sched_barrier(0);
      __builtin_amdgcn_s_barrier();
      const bf16* bb = &Hs[(h + 2) & 3][0];
      QPHASE(acc0, 0, 1, bb)
      if (t > 0) SLICE(car, 3, pslot3, pcolb3, pdiag3)
      QPHASE(acc1, 1, 1, bb)
      SLICE(acc0, 0, t * 128, colb, diag)
      QPHASE(acc2, 2, 1, bb)
      SLICE(acc1, 1, t * 128, colb, diag)
      QPHASE(acc3, 3, 1, bb)
      SLICE(acc2, 2, t * 128, colb, diag)
      car[0] = acc3[0];
      car[1] = acc3[1];
      pslot3 = t * 128;
      pcolb3 = colb;
      pdiag3 = diag;
    }
  }
  SLICE(car, 3, pslot3, pcolb3, pdiag3)   // tile 7's Q3

  // ---- tail: 64 rows x full K in H[2] (staged at h=14, drained h=16).
  if (has_tail) {
    asm volatile("s_waitcnt vmcnt(0)" ::: "memory");
    __builtin_amdgcn_sched_barrier(0);
    __builtin_amdgcn_s_barrier();
    if (wc == 0) {
      const int colb = (ri + 32) * BM + (cj - 2) * 64;
      const bf16* bb = &Hs[2][0];
      #pragma unroll
      for (int Q = 0; Q < 4; ++Q) {
        const int n = Q * 16 + lcol;          // tail row 0..63
        floatx4 ta[2];
        ta[0] = floatx4{0.f, 0.f, 0.f, 0.f};
        ta[1] = floatx4{0.f, 0.f, 0.f, 0.f};
        #pragma unroll
        for (int kq = 0; kq < 8; ++kq) {
          const int kc  = kq * 4 + lquad;
          const int kcs = (kc & 24) | ((kc & 7) ^ (n & 7));
          const bf16x8 b = *(const bf16x8*)(bb + n * 256 + kcs * 8);
          ta[0] = MFMA_(af[0][kq], b, ta[0]);
          ta[1] = MFMA_(af[1][kq], b, ta[1]);
        }
        float cs = 0.f;
        #pragma unroll
        for (int ti = 0; ti < 2; ++ti) {
          #pragma unroll
          for (int r = 0; r < 4; ++r) {
            const float v = ta[ti][r];
            const float e = __builtin_amdgcn_exp2f(v);
            const int rg = row_base + wr + ti * 16 + lquad * 4 + r;
            const int cg = colb + Q * 16 + lcol;
            if (cg == rg + B_ROWS) {                    // positive pair
              const float p = v * 0.6931471805599453f;  // sim/T = v*ln2
              pos[rg] = p;
              pos[cg] = p;
            }
            rowsum[ti][r] += e;
            cs += e;
          }
        }
        cs += __shfl_xor(cs, 16);
        cs += __shfl_xor(cs, 32);
        if (lquad == 0) atomicAdd(&colsum_s[8 * 128 + Q * 16 + lcol], cs);
      }
    }
  }
#undef SLICE
#undef QPHASE
#undef MFMA_

  __syncthreads();  // all ds colsum adds visible; full drain (once)

  // flush colsum_s -> global (one pass, batched atomics)
  #pragma unroll 1
  for (int s = tid; s < 9 * 128; s += 512) {
    const int tile = s >> 7, col = s & 127;
    const float v = colsum_s[s];
    if (tile < 8) {
      if (!(cj == 0 && tile == 0))
        atomicAdd(&sumexp[ct_of(tile) * BM + col], v);
    } else if (has_tail && col < 64) {
      atomicAdd(&sumexp[(ri + 32) * BM + (cj - 2) * 64 + col], v);
    }
  }

  // rowsum: reduce 16 col-lanes, 1 atomic per row per wave
  #pragma unroll
  for (int ti = 0; ti < 2; ++ti) {
    #pragma unroll
    for (int r = 0; r < 4; ++r) {
      float s2 = rowsum[ti][r];
      s2 += __shfl_xor(s2, 1);
      s2 += __shfl_xor(s2, 2);
      s2 += __shfl_xor(s2, 4);
      s2 += __shfl_xor(s2, 8);
      if (lcol == 0) {
        const int grow = row_base + wr + ti * 16 + lquad * 4 + r;
        atomicAdd(&sumexp[grow], s2);
      }
    }
  }
}

// ------------------------------------------------- finalize + mean (1 block)
__global__ __launch_bounds__(1024) void reduce_kernel(
    const float* __restrict__ sumexp, const float* __restrict__ pos,
    float* __restrict__ out) {
  __shared__ float ws[16];
  const int tid = threadIdx.x;
  float s = 0.f;
  const float ln2 = 0.6931471805599453f;
  for (int k = tid; k < N_ROWS; k += 1024)
    s += __builtin_amdgcn_logf(sumexp[k]) * ln2 - pos[k];
  #pragma unroll
  for (int m = 1; m < 64; m <<= 1) s += __shfl_xor(s, m);
  const int wave = tid >> 6, lane = tid & 63;
  if (lane == 0) ws[wave] = s;
  __syncthreads();
  if (wave == 0) {
    float t = (lane < 16) ? ws[lane] : 0.f;
    #pragma unroll
    for (int m = 1; m < 16; m <<= 1) t += __shfl_xor(t, m);
    if (lane == 0) out[0] = t * (1.0f / N_ROWS);
  }
}

extern "C" void kernel_launch(void* const* d_in, const int* in_sizes, int n_in,
                              void* d_out, int out_size, void* d_ws,
                              size_t ws_size, hipStream_t stream) {
  const float* z_i = (const float*)d_in[0];
  const float* z_j = (const float*)d_in[1];
  float* out = (float*)d_out;

  // workspace layout: zn (4 MB bf16) | sumexp (32 KB) | pos (32 KB)
  bf16* zn = (bf16*)d_ws;
  float* sumexp = (float*)((char*)d_ws + (size_t)N_ROWS * D_DIM * sizeof(bf16));
  float* pos = sumexp + N_ROWS;

  normalize_kernel<<<N_ROWS / 4, 256, 0, stream>>>(z_i, z_j, zn, sumexp);
  simexp_kernel<<<256, 512, 0, stream>>>(zn, sumexp, pos);
  reduce_kernel<<<1, 1024, 0, stream>>>(sumexp, pos, out);
}

// Round 9
// 94.276 us; speedup vs baseline: 1.0129x; 1.0129x over previous
//
#include <hip/hip_runtime.h>
#include <hip/hip_bf16.h>
#include <stdint.h>
#include <stddef.h>

// NT-Xent loss, B=4096, D=256, N=8192, T=0.5.
// normalize(+zero sumexp) -> fused symmetric ZZ^T GEMM + exp row/col-sum +
// positive capture -> 1-block finalize/mean. No NxN materialization.
//
// R16: UNLOCK VGPR BUDGET + HALVE LDS-READ AMPLIFICATION. Every profiled
// round showed VGPR_Count pinned at 120/128: our __launch_bounds__(...,2)
// requested the 128-VGPR occupancy cap we then fought (R9/R10 refetch,
// R13 spill). R12==R14==R15 (~33-36 us) across three sync structures =>
// binder is the pipe SUM, dominated by LDS reads: 4x2 layout re-reads B
// frags 4x (256 KB/tile, 3072 cyc > MFMA 2483). Fix (coupled):
//  (a) __launch_bounds__(512, 1) + amdgpu_waves_per_eu(2): cap 256 VGPR,
//      2 waves/SIMD kept (8 waves, 1 block/CU by 128 KB LDS).
//  (b) 2 row-groups x 4 col-groups (wave = 64r x 32c): af[4][8]=128 regs
//      (LDS-bounce pinned), B amplification 2x -> 128 KB/tile LDS reads.
//  (c) phase = 16-col half over full K (8 ds_read_b128 + 32 MFMA); the
//      finished half's exp/sum slice overlaps the next half's MFMAs
//      (R14 mechanism); last half carried one tile (16 regs).
// Carry-overs: R14 skeleton (plain per-tile __syncthreads, stage-early,
// disjoint buffers), A-bounce through LDS, XOR-swizzled conflict-free LDS
// (swizzle on global source), symmetry (2080 tile-pairs), balanced tail
// (s=32 halves on cj2/cj3), exp-scale folded into normalize.

#define B_ROWS 4096
#define D_DIM  256
#define N_ROWS 8192
#define BM 128

typedef __bf16 bf16;
typedef bf16  bf16x8  __attribute__((ext_vector_type(8)));
typedef bf16  bf16x4  __attribute__((ext_vector_type(4)));
typedef float floatx4 __attribute__((ext_vector_type(4)));

// ---------------------------------------------------------------- normalize
__global__ __launch_bounds__(256) void normalize_kernel(
    const float* __restrict__ z_i, const float* __restrict__ z_j,
    bf16* __restrict__ zn, float* __restrict__ sumexp) {
  const int wave = threadIdx.x >> 6;
  const int lane = threadIdx.x & 63;
  const int row  = blockIdx.x * 4 + wave;
  const float* src = (row < B_ROWS) ? (z_i + (size_t)row * D_DIM)
                                    : (z_j + (size_t)(row - B_ROWS) * D_DIM);
  float4 v = ((const float4*)src)[lane];
  float ss = v.x * v.x + v.y * v.y + v.z * v.z + v.w * v.w;
  #pragma unroll
  for (int m = 1; m < 64; m <<= 1) ss += __shfl_xor(ss, m);
  const float rn = rsqrtf(ss) * 1.6986436f;  // * sqrt(2/ln2)
  bf16x4 o;
  o[0] = (bf16)(v.x * rn);
  o[1] = (bf16)(v.y * rn);
  o[2] = (bf16)(v.z * rn);
  o[3] = (bf16)(v.w * rn);
  ((bf16x4*)(zn + (size_t)row * D_DIM))[lane] = o;
  if (lane == 0) sumexp[row] = 0.f;
}

// ------------------------------------------------------- fused sim+exp+sum
// Grid: 64 ri x 4 cj = 256 blocks (1/CU by 128 KB LDS). Block (ri,cj): 8
// tiles s=8cj+t; (ri<32, cj>=2) add the j64-half (cj-2) of s=32 (tail).
// 8 waves in 2x4 (wave = 64 rows x 32 cols); af[4][8] register-resident.
// LDS: 16B chunk of row n, k-chunk kc at slot n*32 + ((kc&24)|((kc&7)^
// (n&7))); swizzle applied on the GLOBAL source (LDS dest linear).
__global__ __launch_bounds__(512, 1)
__attribute__((amdgpu_waves_per_eu(2)))
void simexp_kernel(
    const bf16* __restrict__ zn, float* __restrict__ sumexp,
    float* __restrict__ pos) {
  __shared__ __align__(16) bf16 Bs[2][BM * D_DIM];  // 2 x 64 KB

  const int tid   = threadIdx.x;
  const int wave  = tid >> 6;
  const int lane  = tid & 63;
  const int lcol  = lane & 15;   // MFMA: A row / B col / C col
  const int lquad = lane >> 4;   // MFMA: k-group / C row-group
  const int wr = (wave >> 2) * 64;  // wave row offset: 0,64
  const int wc = (wave & 3) * 32;   // wave col offset: 0,32,64,96
  const int ri = blockIdx.x >> 2;
  const int cj = blockIdx.x & 3;
  const int row_base = ri * BM;
  const bool has_tail = (ri < 32 && cj >= 2);

  auto ct_of = [&](int t) { return (ri + 8 * cj + t) & 63; };

  // stage rows of a tile into Bs[buf]: chunk slot s=it*512+tid, row n=s>>5,
  // swizzled k-chunk; coalesced 16B global_load_lds, source pre-swizzled.
  auto stageB = [&](int buf, const bf16* src, int it0, int it1) {
    for (int it = it0; it < it1; ++it) {
      const int s   = it * 512 + tid;
      const int n   = s >> 5;
      const int kcs = s & 31;
      const int kc  = (kcs & 24) | ((kcs & 7) ^ (n & 7));
      __builtin_amdgcn_global_load_lds(
          (const __attribute__((address_space(1))) unsigned int*)
              (src + (size_t)n * D_DIM + kc * 8),
          (__attribute__((address_space(3))) unsigned int*)&Bs[buf][s * 8],
          16, 0, 0);
    }
  };

  // ---- prologue: A tile -> buf0, first B tile -> buf1, overlapped.
  stageB(0, zn + (size_t)row_base * D_DIM, 0, 8);
  stageB(1, zn + (size_t)ct_of(0) * BM * D_DIM, 0, 8);
  __syncthreads();  // vmcnt(0): both tiles resident

  // af[ti][kq]: row = row_base+wr+ti*16+lcol (ti 0..3 -> 64 rows), k =
  // kq*32+lquad*8..+7. buf0 overwritten later -> af pinned in registers.
  floatx4 af[4][8];
  #pragma unroll
  for (int ti = 0; ti < 4; ++ti) {
    const int n = wr + ti * 16 + lcol;
    #pragma unroll
    for (int kq = 0; kq < 8; ++kq) {
      const int kc  = kq * 4 + lquad;
      const int kcs = (kc & 24) | ((kc & 7) ^ (n & 7));
      af[ti][kq] = *(const floatx4*)(&Bs[0][(n * 32 + kcs) * 8]);
    }
  }
  __syncthreads();  // af reads done -> buf0 free for staging

  float rowsum[4][4];  // [ti][r]; row = wr + ti*16 + lquad*4 + r
  #pragma unroll
  for (int ti = 0; ti < 4; ++ti)
    #pragma unroll
    for (int r = 0; r < 4; ++r) rowsum[ti][r] = 0.f;

#define MFMA_(A, B_, C) __builtin_amdgcn_mfma_f32_16x16x32_bf16( \
    __builtin_bit_cast(bf16x8, A), B_, C, 0, 0, 0)

  // one 16-col half over full K: 8 ds_read_b128 + 32 MFMA into ACC[4]
#define PHASE_(ACC, NCOL, BB)                                             \
  {                                                                       \
    const int n = (NCOL);                                                 \
    bf16x8 bfr[8];                                                        \
    _Pragma("unroll")                                                     \
    for (int kq = 0; kq < 8; ++kq) {                                      \
      const int kc  = kq * 4 + lquad;                                     \
      const int kcs = (kc & 24) | ((kc & 7) ^ (n & 7));                   \
      bfr[kq] = *(const bf16x8*)((BB) + n * D_DIM + kcs * 8);             \
    }                                                                     \
    _Pragma("unroll")                                                     \
    for (int ti = 0; ti < 4; ++ti) ACC[ti] = floatx4{0.f, 0.f, 0.f, 0.f}; \
    _Pragma("unroll")                                                     \
    for (int kq = 0; kq < 8; ++kq) {                                      \
      _Pragma("unroll")                                                   \
      for (int ti = 0; ti < 4; ++ti)                                      \
        ACC[ti] = MFMA_(af[ti][kq], bfr[kq], ACC[ti]);                    \
    }                                                                     \
  }

  // epilogue slice of a finished col-half: exp + rowsum + colsum atomic.
  // CGB = col_base + wc + tj*16; column of lane = CGB + lcol.
#define SLICE(ACC, CGB, DG)                                               \
  {                                                                       \
    float cs = 0.f;                                                       \
    _Pragma("unroll")                                                     \
    for (int ti = 0; ti < 4; ++ti) {                                      \
      _Pragma("unroll")                                                   \
      for (int r = 0; r < 4; ++r) {                                       \
        const float v = ACC[ti][r];                                       \
        float e = __builtin_amdgcn_exp2f(v);                              \
        if (DG) {                                                         \
          const int rg = row_base + wr + ti * 16 + lquad * 4 + r;         \
          const int cg = (CGB) + lcol;                                    \
          if (cg == rg) e = 0.f;  /* mask self-similarity */              \
        }                                                                 \
        rowsum[ti][r] += e;                                               \
        cs += e;                                                          \
      }                                                                   \
    }                                                                     \
    cs += __shfl_xor(cs, 16);                                             \
    cs += __shfl_xor(cs, 32);                                             \
    if (!(DG) && lquad == 0) atomicAdd(&sumexp[(CGB) + lcol], cs);        \
  }

  floatx4 accA[4], accB[4], carry[4];
  int  pcgb  = 0;
  bool pdiag = false;

  #pragma unroll 1  // one body copy (I$); single barrier per tile
  for (int t = 0; t < 8; ++t) {
    const bf16* bbase = &Bs[(t + 1) & 1][0];  // compute buffer
    const int sb = t & 1;                     // stage buffer (disjoint)
    if (t < 7) {
      stageB(sb, zn + (size_t)ct_of(t + 1) * BM * D_DIM, 0, 8);
    } else if (has_tail) {
      stageB(sb, zn + (size_t)((ri + 32) * BM + (cj - 2) * 64) * D_DIM, 0, 4);
    }
    const int  colb = ct_of(t) * BM;
    const bool diag = (cj == 0 && t == 0);

    PHASE_(accA, wc + lcol, bbase)
    if (t > 0) SLICE(carry, pcgb, pdiag)      // prev tile's second half
    PHASE_(accB, wc + 16 + lcol, bbase)
    SLICE(accA, colb + wc, diag)              // first half, overlapped
    #pragma unroll
    for (int ti = 0; ti < 4; ++ti) carry[ti] = accB[ti];
    pcgb  = colb + wc + 16;
    pdiag = diag;
    __syncthreads();  // vmcnt(0)+barrier: stage done, buffer swap safe
  }
  SLICE(carry, pcgb, pdiag)   // tile 7's second half

  // ---- tail: j64-half (cj-2) of the s=32 tile, in Bs[1] (staged during
  // tile 7, drained by its __syncthreads; never rewritten). Positive pairs
  // live exactly here: cg == rg + B_ROWS. Waves with (wave&3)<2 cover
  // 128 rows x 64 cols.
  if (has_tail && (wave & 3) < 2) {
    const int colb = (ri + 32) * BM + (cj - 2) * 64;
    const bf16* bbase = &Bs[1][0];
    floatx4 ta[4];
    #pragma unroll
    for (int tj = 0; tj < 2; ++tj) {
      PHASE_(ta, wc + tj * 16 + lcol, bbase)  // tail rows 0..63 staged
      float cs = 0.f;
      #pragma unroll
      for (int ti = 0; ti < 4; ++ti) {
        #pragma unroll
        for (int r = 0; r < 4; ++r) {
          const float v = ta[ti][r];
          const float e = __builtin_amdgcn_exp2f(v);
          const int rg = row_base + wr + ti * 16 + lquad * 4 + r;
          const int cg = colb + wc + tj * 16 + lcol;
          if (cg == rg + B_ROWS) {                    // positive pair
            const float p = v * 0.6931471805599453f;  // sim/T = v*ln2
            pos[rg] = p;
            pos[cg] = p;
          }
          rowsum[ti][r] += e;
          cs += e;
        }
      }
      cs += __shfl_xor(cs, 16);
      cs += __shfl_xor(cs, 32);
      if (lquad == 0) atomicAdd(&sumexp[colb + wc + tj * 16 + lcol], cs);
    }
  }
#undef SLICE
#undef PHASE_
#undef MFMA_

  // rowsum: reduce 16 col-lanes, 1 atomic per row per wave
  #pragma unroll
  for (int ti = 0; ti < 4; ++ti) {
    #pragma unroll
    for (int r = 0; r < 4; ++r) {
      float s2 = rowsum[ti][r];
      s2 += __shfl_xor(s2, 1);
      s2 += __shfl_xor(s2, 2);
      s2 += __shfl_xor(s2, 4);
      s2 += __shfl_xor(s2, 8);
      if (lcol == 0) {
        const int grow = row_base + wr + ti * 16 + lquad * 4 + r;
        atomicAdd(&sumexp[grow], s2);
      }
    }
  }
}

// ------------------------------------------------- finalize + mean (1 block)
__global__ __launch_bounds__(1024) void reduce_kernel(
    const float* __restrict__ sumexp, const float* __restrict__ pos,
    float* __restrict__ out) {
  __shared__ float ws[16];
  const int tid = threadIdx.x;
  float s = 0.f;
  const float ln2 = 0.6931471805599453f;
  for (int k = tid; k < N_ROWS; k += 1024)
    s += __builtin_amdgcn_logf(sumexp[k]) * ln2 - pos[k];
  #pragma unroll
  for (int m = 1; m < 64; m <<= 1) s += __shfl_xor(s, m);
  const int wave = tid >> 6, lane = tid & 63;
  if (lane == 0) ws[wave] = s;
  __syncthreads();
  if (wave == 0) {
    float t = (lane < 16) ? ws[lane] : 0.f;
    #pragma unroll
    for (int m = 1; m < 16; m <<= 1) t += __shfl_xor(t, m);
    if (lane == 0) out[0] = t * (1.0f / N_ROWS);
  }
}

extern "C" void kernel_launch(void* const* d_in, const int* in_sizes, int n_in,
                              void* d_out, int out_size, void* d_ws,
                              size_t ws_size, hipStream_t stream) {
  const float* z_i = (const float*)d_in[0];
  const float* z_j = (const float*)d_in[1];
  float* out = (float*)d_out;

  // workspace layout: zn (4 MB bf16) | sumexp (32 KB) | pos (32 KB)
  bf16* zn = (bf16*)d_ws;
  float* sumexp = (float*)((char*)d_ws + (size_t)N_ROWS * D_DIM * sizeof(bf16));
  float* pos = sumexp + N_ROWS;

  normalize_kernel<<<N_ROWS / 4, 256, 0, stream>>>(z_i, z_j, zn, sumexp);
  simexp_kernel<<<256, 512, 0, stream>>>(zn, sumexp, pos);
  reduce_kernel<<<1, 1024, 0, stream>>>(sumexp, pos, out);
}